// Round 2
// baseline (76.485 us; speedup 1.0000x reference)
//
#include <hip/hip_runtime.h>
#include <hip/hip_bf16.h>

#define HW 9216   // 96*96
#define CIN 128
#define COUT 128

#if __has_builtin(__builtin_amdgcn_exp2f)
#define EXP2F(x) __builtin_amdgcn_exp2f(x)
#else
#define EXP2F(x) exp2f(x)
#endif

// ---------------- Kernel 1: q = w_q @ x, k = w_k @ x ----------------
// grid (288, 2, 2): 32-pixel strip, batch, z selects (wq->qbuf | wk->kbuf).
// block 256: og = tid>>4 (8 outs each), pg = tid&15 (2 pixels each).
// Weights streamed from global (L2-resident, lanes with same og dedup);
// x staged once in LDS as [k][pix] (conflict-free b64 reads).
__global__ __launch_bounds__(256) void conv1x1_v2(
    const float* __restrict__ x,   // [2][128][9216]
    const float* __restrict__ wq,  // [128][128] (o, i)
    const float* __restrict__ wk,
    float* __restrict__ qbuf,      // [2][128][9216]
    float* __restrict__ kbuf)
{
    __shared__ __align__(16) float xs[128 * 32];   // [k][p]

    const int tid = threadIdx.x;
    const int b = blockIdx.y;
    const int pixbase = blockIdx.x * 32;
    const int z = blockIdx.z;

    const float* xb = x + (size_t)b * CIN * HW + pixbase;
    #pragma unroll
    for (int i = 0; i < 16; ++i) {
        int flat = tid + i * 256;
        int kk = flat >> 5, p = flat & 31;
        xs[flat] = xb[kk * HW + p];
    }
    __syncthreads();

    const int og = tid >> 4;   // 0..15 -> outs og*8..+7
    const int pg = tid & 15;   // 0..15 -> pixels pg*2, pg*2+1
    const float* wbase = (z ? wk : wq) + og * 8 * 128;
    float* obuf = z ? kbuf : qbuf;

    float acc[8][2];
    #pragma unroll
    for (int j = 0; j < 8; ++j) { acc[j][0] = 0.f; acc[j][1] = 0.f; }

    #pragma unroll 4
    for (int kb = 0; kb < 128; kb += 4) {
        float4 wv[8];
        #pragma unroll
        for (int j = 0; j < 8; ++j)
            wv[j] = *(const float4*)&wbase[j * 128 + kb];
        float2 xv[4];
        #pragma unroll
        for (int t = 0; t < 4; ++t)
            xv[t] = *(const float2*)&xs[(kb + t) * 32 + pg * 2];
        #pragma unroll
        for (int j = 0; j < 8; ++j) {
            acc[j][0] = fmaf(wv[j].x, xv[0].x, acc[j][0]);
            acc[j][1] = fmaf(wv[j].x, xv[0].y, acc[j][1]);
            acc[j][0] = fmaf(wv[j].y, xv[1].x, acc[j][0]);
            acc[j][1] = fmaf(wv[j].y, xv[1].y, acc[j][1]);
            acc[j][0] = fmaf(wv[j].z, xv[2].x, acc[j][0]);
            acc[j][1] = fmaf(wv[j].z, xv[2].y, acc[j][1]);
            acc[j][0] = fmaf(wv[j].w, xv[3].x, acc[j][0]);
            acc[j][1] = fmaf(wv[j].w, xv[3].y, acc[j][1]);
        }
    }

    #pragma unroll
    for (int j = 0; j < 8; ++j) {
        float2 o2 = {acc[j][0], acc[j][1]};
        *(float2*)&obuf[((size_t)b * COUT + og * 8 + j) * HW + pixbase + pg * 2] = o2;
    }
}

// ---------------- Kernel 2: windowed softmax attention v2 ----------------
// grid (6, 256): 16 full-width rows per block, one (b,c) plane per blockIdx.y.
// block 192 = 12 col-groups (8 outputs each) x 16 rows. rel folded into the
// exponent: exp2(q2*k + q2*rel) via fma (is_h) / mul of sum (is_w).
__global__ __launch_bounds__(192) void attn_v2(
    const float* __restrict__ qbuf,
    const float* __restrict__ kbuf,
    const float* __restrict__ v,
    const float* __restrict__ rel_h,  // [64][7]
    const float* __restrict__ rel_w,  // [64][7]
    float* __restrict__ out)
{
    __shared__ __align__(16) float ks[22 * 104];
    __shared__ __align__(16) float vs[22 * 104];

    const int tid = threadIdx.x;
    const int th = blockIdx.x * 16;
    const int bc = blockIdx.y;
    const int c = bc & 127;

    const float* kp = kbuf + (size_t)bc * HW;
    const float* vp = v    + (size_t)bc * HW;

    // halo: rows th-3..th+18 (22), cols -3..98 (102), zero padded
    for (int idx = tid; idx < 22 * 102; idx += 192) {
        int r = idx / 102, cl = idx - r * 102;
        int gr = th - 3 + r, gc = cl - 3;
        bool ok = ((unsigned)gr < 96u) && ((unsigned)gc < 96u);
        float kv = ok ? kp[gr * 96 + gc] : 0.f;
        float vv = ok ? vp[gr * 96 + gc] : 0.f;
        ks[r * 104 + cl] = kv;
        vs[r * 104 + cl] = vv;
    }

    const bool is_h = (c < 64);
    const float* rbase = is_h ? (rel_h + c * 7) : (rel_w + (c - 64) * 7);
    float r7[7];
    #pragma unroll
    for (int i = 0; i < 7; ++i) r7[i] = rbase[i];

    const int ty = tid / 12;       // 0..15 (row)
    const int tx = tid - ty * 12;  // 0..11 (col group of 8)

    const float* qrow = qbuf + (size_t)bc * HW + (th + ty) * 96 + tx * 8;
    float4 qa = *(const float4*)qrow;
    float4 qb = *(const float4*)(qrow + 4);
    const float L2E = 1.4426950408889634f;
    float q2[8] = {qa.x * L2E, qa.y * L2E, qa.z * L2E, qa.w * L2E,
                   qb.x * L2E, qb.y * L2E, qb.z * L2E, qb.w * L2E};

    float s[8], a[8];
    #pragma unroll
    for (int j = 0; j < 8; ++j) { s[j] = 0.f; a[j] = 0.f; }

    __syncthreads();

    for (int dh = 0; dh < 7; ++dh) {
        const float* krow = &ks[(ty + dh) * 104 + tx * 8];
        const float* vrow = &vs[(ty + dh) * 104 + tx * 8];
        float kr[16], vr[16];
        #pragma unroll
        for (int t = 0; t < 4; ++t) {
            *(float4*)&kr[t * 4] = *(const float4*)&krow[t * 4];
            *(float4*)&vr[t * 4] = *(const float4*)&vrow[t * 4];
        }

        if (is_h) {
            float rh = r7[dh];
            #pragma unroll
            for (int j = 0; j < 8; ++j) {
                float qr = q2[j] * rh;
                #pragma unroll
                for (int dw = 0; dw < 7; ++dw) {
                    float e = EXP2F(fmaf(q2[j], kr[j + dw], qr));
                    s[j] += e;
                    a[j] = fmaf(e, vr[j + dw], a[j]);
                }
            }
        } else {
            #pragma unroll
            for (int j = 0; j < 8; ++j) {
                #pragma unroll
                for (int dw = 0; dw < 7; ++dw) {
                    float e = EXP2F(q2[j] * (kr[j + dw] + r7[dw]));
                    s[j] += e;
                    a[j] = fmaf(e, vr[j + dw], a[j]);
                }
            }
        }
    }

    float* orow = out + (size_t)bc * HW + (th + ty) * 96 + tx * 8;
    float4 o0 = {a[0] / s[0], a[1] / s[1], a[2] / s[2], a[3] / s[3]};
    float4 o1 = {a[4] / s[4], a[5] / s[5], a[6] / s[6], a[7] / s[7]};
    *(float4*)orow = o0;
    *(float4*)(orow + 4) = o1;
}

extern "C" void kernel_launch(void* const* d_in, const int* in_sizes, int n_in,
                              void* d_out, int out_size, void* d_ws, size_t ws_size,
                              hipStream_t stream) {
    const float* x  = (const float*)d_in[0];
    const float* v  = (const float*)d_in[1];
    const float* wq = (const float*)d_in[2];
    const float* wk = (const float*)d_in[3];
    const float* rh = (const float*)d_in[4];
    const float* rw = (const float*)d_in[5];
    float* out = (float*)d_out;

    float* qbuf = (float*)d_ws;                       // 2*128*9216 f32
    float* kbuf = qbuf + (size_t)2 * COUT * HW;       // 2*128*9216 f32

    conv1x1_v2<<<dim3(288, 2, 2), 256, 0, stream>>>(x, wq, wk, qbuf, kbuf);
    attn_v2<<<dim3(6, 256), 192, 0, stream>>>(qbuf, kbuf, v, rh, rw, out);
}

// Round 3
// 66.996 us; speedup vs baseline: 1.1416x; 1.1416x over previous
//
#include <hip/hip_runtime.h>
#include <hip/hip_bf16.h>

#define HW 9216   // 96*96
#define CIN 128
#define COUT 128

__device__ __forceinline__ float fast_exp2(float x) {
    float r;
    asm volatile("v_exp_f32 %0, %1" : "=v"(r) : "v"(x));
    return r;
}

// ---------------- Kernel 1: q = w_q @ x, k = w_k @ x (v3) ----------------
// grid (36, 2, 8): x = 256-pixel strip, y = batch, z = ot*2 + zsel.
// block 256 = 4 waves; wave owns 8 outs, lane owns 4 consecutive pixels.
// w tile (32 outs x 128 k, 16 KB) staged once in LDS, read as wave-uniform
// b128 broadcasts. x staged in 16-k chunks (16 KB) with register prefetch.
__global__ __launch_bounds__(256) void conv1x1_v3(
    const float* __restrict__ x,   // [2][128][9216]
    const float* __restrict__ wq,  // [128][128] (o, i)
    const float* __restrict__ wk,
    float* __restrict__ qbuf,      // [2][128][9216]
    float* __restrict__ kbuf)
{
    __shared__ __align__(16) float xs[16 * 256];   // [k_local][pix] 16 KB
    __shared__ __align__(16) float wls[32 * 128];  // [o_local][k]   16 KB

    const int tid = threadIdx.x;
    const int pixbase = blockIdx.x * 256;
    const int b = blockIdx.y;
    const int z2 = blockIdx.z;
    const int zsel = z2 & 1;
    const int ot = z2 >> 1;            // 0..3 -> out base ot*32

    const float* wsel = zsel ? wk : wq;
    float* obuf = zsel ? kbuf : qbuf;

    // stage w tile [32][128] (straight copy, coalesced)
    {
        const float* wsrc = wsel + ot * 32 * 128;
        #pragma unroll
        for (int i = 0; i < 4; ++i) {
            int f4 = tid + i * 256;
            *(float4*)&wls[f4 * 4] = *(const float4*)&wsrc[f4 * 4];
        }
    }

    const float* xb = x + (size_t)b * CIN * HW + pixbase;
    const int wave = __builtin_amdgcn_readfirstlane(tid >> 6);
    const int lane = tid & 63;

    float acc[8][4];
    #pragma unroll
    for (int j = 0; j < 8; ++j)
        #pragma unroll
        for (int p = 0; p < 4; ++p) acc[j][p] = 0.f;

    // prefetch chunk 0 into registers
    float4 st[4];
    #pragma unroll
    for (int i = 0; i < 4; ++i) {
        int f4 = tid + i * 256;                 // row = f4>>6 (0..15), col4 = f4&63
        st[i] = *(const float4*)&xb[(f4 >> 6) * HW + (f4 & 63) * 4];
    }

    for (int kb = 0; kb < 128; kb += 16) {
        __syncthreads();                        // xs consumers of prev chunk done
        #pragma unroll
        for (int i = 0; i < 4; ++i) {
            int f4 = tid + i * 256;
            *(float4*)&xs[f4 * 4] = st[i];
        }
        __syncthreads();
        if (kb + 16 < 128) {
            #pragma unroll
            for (int i = 0; i < 4; ++i) {
                int f4 = tid + i * 256;
                st[i] = *(const float4*)&xb[(kb + 16 + (f4 >> 6)) * HW + (f4 & 63) * 4];
            }
        }
        #pragma unroll
        for (int k4 = 0; k4 < 4; ++k4) {
            float4 wr[8];
            #pragma unroll
            for (int j = 0; j < 8; ++j)
                wr[j] = *(const float4*)&wls[(wave * 8 + j) * 128 + kb + k4 * 4];
            #pragma unroll
            for (int kk = 0; kk < 4; ++kk) {
                float4 xv = *(const float4*)&xs[(k4 * 4 + kk) * 256 + lane * 4];
                #pragma unroll
                for (int j = 0; j < 8; ++j) {
                    float w = ((const float*)&wr[j])[kk];
                    acc[j][0] = fmaf(w, xv.x, acc[j][0]);
                    acc[j][1] = fmaf(w, xv.y, acc[j][1]);
                    acc[j][2] = fmaf(w, xv.z, acc[j][2]);
                    acc[j][3] = fmaf(w, xv.w, acc[j][3]);
                }
            }
        }
    }

    #pragma unroll
    for (int j = 0; j < 8; ++j) {
        float4 o4 = {acc[j][0], acc[j][1], acc[j][2], acc[j][3]};
        *(float4*)&obuf[((size_t)b * COUT + ot * 32 + wave * 8 + j) * HW
                        + pixbase + lane * 4] = o4;
    }
}

// ---------------- Kernel 2: windowed softmax attention v3 ----------------
// grid (6, 256): 16 full-width rows per block, one (b,c) plane per blockIdx.y.
// block 192 = 12 col-groups (8 outputs each) x 16 rows. Raw v_exp_f32 + rcp.
__global__ __launch_bounds__(192) void attn_v3(
    const float* __restrict__ qbuf,
    const float* __restrict__ kbuf,
    const float* __restrict__ v,
    const float* __restrict__ rel_h,  // [64][7]
    const float* __restrict__ rel_w,  // [64][7]
    float* __restrict__ out)
{
    __shared__ __align__(16) float ks[22 * 104];
    __shared__ __align__(16) float vs[22 * 104];

    const int tid = threadIdx.x;
    const int th = blockIdx.x * 16;
    const int bc = blockIdx.y;
    const int c = bc & 127;

    const float* kp = kbuf + (size_t)bc * HW;
    const float* vp = v    + (size_t)bc * HW;

    for (int idx = tid; idx < 22 * 102; idx += 192) {
        int r = idx / 102, cl = idx - r * 102;
        int gr = th - 3 + r, gc = cl - 3;
        bool ok = ((unsigned)gr < 96u) && ((unsigned)gc < 96u);
        float kv = ok ? kp[gr * 96 + gc] : 0.f;
        float vv = ok ? vp[gr * 96 + gc] : 0.f;
        ks[r * 104 + cl] = kv;
        vs[r * 104 + cl] = vv;
    }

    const bool is_h = (c < 64);
    const float* rbase = is_h ? (rel_h + c * 7) : (rel_w + (c - 64) * 7);
    float r7[7];
    #pragma unroll
    for (int i = 0; i < 7; ++i) r7[i] = rbase[i];

    const int ty = tid / 12;       // 0..15 (row)
    const int tx = tid - ty * 12;  // 0..11 (col group of 8)

    const float* qrow = qbuf + (size_t)bc * HW + (th + ty) * 96 + tx * 8;
    float4 qa = *(const float4*)qrow;
    float4 qb = *(const float4*)(qrow + 4);
    const float L2E = 1.4426950408889634f;
    float q2[8] = {qa.x * L2E, qa.y * L2E, qa.z * L2E, qa.w * L2E,
                   qb.x * L2E, qb.y * L2E, qb.z * L2E, qb.w * L2E};

    float s[8], a[8];
    #pragma unroll
    for (int j = 0; j < 8; ++j) { s[j] = 0.f; a[j] = 0.f; }

    __syncthreads();

    const float* krow = &ks[ty * 104 + tx * 8];
    const float* vrow = &vs[ty * 104 + tx * 8];

    #pragma unroll
    for (int dh = 0; dh < 7; ++dh) {
        float kr[16], vr[16];
        #pragma unroll
        for (int t = 0; t < 4; ++t) {
            *(float4*)&kr[t * 4] = *(const float4*)&krow[t * 4];
            *(float4*)&vr[t * 4] = *(const float4*)&vrow[t * 4];
        }
        krow += 104;
        vrow += 104;

        if (is_h) {
            float rh = r7[dh];
            #pragma unroll
            for (int j = 0; j < 8; ++j) {
                float qr = q2[j] * rh;
                #pragma unroll
                for (int dw = 0; dw < 7; ++dw) {
                    float e = fast_exp2(fmaf(q2[j], kr[j + dw], qr));
                    s[j] += e;
                    a[j] = fmaf(e, vr[j + dw], a[j]);
                }
            }
        } else {
            #pragma unroll
            for (int j = 0; j < 8; ++j) {
                #pragma unroll
                for (int dw = 0; dw < 7; ++dw) {
                    float e = fast_exp2(q2[j] * (kr[j + dw] + r7[dw]));
                    s[j] += e;
                    a[j] = fmaf(e, vr[j + dw], a[j]);
                }
            }
        }
    }

    float* orow = out + (size_t)bc * HW + (th + ty) * 96 + tx * 8;
    float4 o0, o1;
    o0.x = a[0] * __builtin_amdgcn_rcpf(s[0]);
    o0.y = a[1] * __builtin_amdgcn_rcpf(s[1]);
    o0.z = a[2] * __builtin_amdgcn_rcpf(s[2]);
    o0.w = a[3] * __builtin_amdgcn_rcpf(s[3]);
    o1.x = a[4] * __builtin_amdgcn_rcpf(s[4]);
    o1.y = a[5] * __builtin_amdgcn_rcpf(s[5]);
    o1.z = a[6] * __builtin_amdgcn_rcpf(s[6]);
    o1.w = a[7] * __builtin_amdgcn_rcpf(s[7]);
    *(float4*)orow = o0;
    *(float4*)(orow + 4) = o1;
}

extern "C" void kernel_launch(void* const* d_in, const int* in_sizes, int n_in,
                              void* d_out, int out_size, void* d_ws, size_t ws_size,
                              hipStream_t stream) {
    const float* x  = (const float*)d_in[0];
    const float* v  = (const float*)d_in[1];
    const float* wq = (const float*)d_in[2];
    const float* wk = (const float*)d_in[3];
    const float* rh = (const float*)d_in[4];
    const float* rw = (const float*)d_in[5];
    float* out = (float*)d_out;

    float* qbuf = (float*)d_ws;                       // 2*128*9216 f32
    float* kbuf = qbuf + (size_t)2 * COUT * HW;       // 2*128*9216 f32

    conv1x1_v3<<<dim3(36, 2, 8), 256, 0, stream>>>(x, wq, wk, qbuf, kbuf);
    attn_v3<<<dim3(6, 256), 192, 0, stream>>>(qbuf, kbuf, v, rh, rw, out);
}

// Round 4
// 51.719 us; speedup vs baseline: 1.4789x; 1.2954x over previous
//
#include <hip/hip_runtime.h>
#include <hip/hip_bf16.h>

#define HW 9216   // 96*96
#define CIN 128
#define COUT 128

typedef _Float16 half8 __attribute__((ext_vector_type(8)));
typedef float f32x4 __attribute__((ext_vector_type(4)));

__device__ __forceinline__ float fast_exp2(float x) {
    float r;
    asm volatile("v_exp_f32 %0, %1" : "=v"(r) : "v"(x));
    return r;
}

__device__ __forceinline__ void mfma16(f32x4& d, half8 a, half8 b) {
    asm("v_mfma_f32_16x16x32_f16 %0, %1, %2, %0" : "+v"(d) : "v"(a), "v"(b));
}

__device__ __forceinline__ void gl_lds16(const void* g, void* l) {
    __builtin_amdgcn_global_load_lds(
        (const __attribute__((address_space(1))) unsigned int*)g,
        (__attribute__((address_space(3))) unsigned int*)l, 16, 0, 0);
}

__device__ __forceinline__ unsigned short h_bits(_Float16 h) {
    return __builtin_bit_cast(unsigned short, h);
}

// ---------------- Kernel 0: prep ----------------
// blocks 0..143 (x transpose+convert): x[b][k][p] f32 -> xh_t/xl_t[b][p][k^((p&7)<<3)] f16
// blocks 144..151 (w convert): wq/wk [o][k] f32 -> wh_t/wl_t[o][k^((o&7)<<3)] f16
__global__ __launch_bounds__(256) void prep(
    const float* __restrict__ x,
    const float* __restrict__ wq, const float* __restrict__ wk,
    _Float16* __restrict__ xh_t, _Float16* __restrict__ xl_t,
    _Float16* __restrict__ wh_t, _Float16* __restrict__ wl_t)
{
    const int tid = threadIdx.x;
    const int bx = blockIdx.x;
    const int b = blockIdx.y;

    if (bx >= 144) {
        if (b) return;
        // w: 8 blocks x 32 rows
        int o = (bx - 144) * 32 + (tid >> 3);
        int k0 = (tid & 7) * 16;
        const float* src = (o < 128) ? (wq + o * 128) : (wk + (o - 128) * 128);
        float vals[16];
        #pragma unroll
        for (int t = 0; t < 4; ++t)
            *(float4*)&vals[t * 4] = *(const float4*)&src[k0 + t * 4];
        half8 h0, h1, l0, l1;
        #pragma unroll
        for (int j = 0; j < 8; ++j) {
            _Float16 h = (_Float16)vals[j];
            h0[j] = h; l0[j] = (_Float16)(vals[j] - (float)h);
            _Float16 h2 = (_Float16)vals[j + 8];
            h1[j] = h2; l1[j] = (_Float16)(vals[j + 8] - (float)h2);
        }
        int s = (o & 7) << 3;
        *(half8*)&wh_t[o * 128 + (k0 ^ s)]       = h0;
        *(half8*)&wh_t[o * 128 + ((k0 + 8) ^ s)] = h1;
        *(half8*)&wl_t[o * 128 + (k0 ^ s)]       = l0;
        *(half8*)&wl_t[o * 128 + ((k0 + 8) ^ s)] = l1;
        return;
    }

    __shared__ unsigned int lds[64 * 128];   // [p][k] packed h|l<<16, idx ^= (p&31)
    const int pixbase = bx * 64;
    const int p = tid & 63;
    const int kw = tid >> 6;
    const float* xb = x + (size_t)b * CIN * HW + pixbase + p;

    #pragma unroll
    for (int i = 0; i < 32; ++i) {
        int k = kw * 32 + i;
        float v = xb[(size_t)k * HW];
        _Float16 h = (_Float16)v;
        _Float16 l = (_Float16)(v - (float)h);
        unsigned int pack = (unsigned int)h_bits(h) | ((unsigned int)h_bits(l) << 16);
        lds[(p * 128 + k) ^ (p & 31)] = pack;
    }
    __syncthreads();

    const int p2 = tid >> 2;
    const int qk = (tid & 3) * 32;
    const int s = (p2 & 7) << 3;
    unsigned int hw_[16], lw_[16];
    #pragma unroll
    for (int i = 0; i < 16; ++i) {
        int pos0 = qk + 2 * i;
        int src0 = pos0 ^ s;       // s touches bits 3..5 only; pairs preserved
        unsigned int a0 = lds[(p2 * 128 + src0) ^ (p2 & 31)];
        unsigned int a1 = lds[(p2 * 128 + src0 + 1) ^ (p2 & 31)];
        hw_[i] = (a0 & 0xffffu) | (a1 << 16);
        lw_[i] = (a0 >> 16) | (a1 & 0xffff0000u);
    }
    size_t orow = ((size_t)b * HW + pixbase + p2) * 64 + (qk >> 1);  // u32 units
    unsigned int* oh = (unsigned int*)xh_t;
    unsigned int* ol = (unsigned int*)xl_t;
    #pragma unroll
    for (int i = 0; i < 4; ++i) {
        uint4 th = {hw_[i*4], hw_[i*4+1], hw_[i*4+2], hw_[i*4+3]};
        uint4 tl = {lw_[i*4], lw_[i*4+1], lw_[i*4+2], lw_[i*4+3]};
        *(uint4*)&oh[orow + i * 4] = th;
        *(uint4*)&ol[orow + i * 4] = tl;
    }
}

// ---------------- Kernel 1: conv via f16-split MFMA ----------------
// grid (72, 2, 4): 128-pix strip, batch, 64-out tile (z<2 -> q, else k).
// block 256 = 4 waves, wave tile 32 out x 64 pix = 2x4 MFMA 16x16 tiles.
// K chunks of 64; LDS 48KB staged via global_load_lds (pre-swizzled source).
__global__ __launch_bounds__(256) void conv_mfma(
    const _Float16* __restrict__ xh_t, const _Float16* __restrict__ xl_t,
    const _Float16* __restrict__ wh_t, const _Float16* __restrict__ wl_t,
    float* __restrict__ qbuf, float* __restrict__ kbuf)
{
    __shared__ _Float16 xsh[128 * 64];
    __shared__ _Float16 xsl[128 * 64];
    __shared__ _Float16 wsh[64 * 64];
    __shared__ _Float16 wsl[64 * 64];

    const int tid = threadIdx.x;
    const int lane = tid & 63;
    const int wave = tid >> 6;
    const int pixbase = blockIdx.x * 128;
    const int b = blockIdx.y;
    const int mt = blockIdx.z;
    const int outbase = mt * 64;

    const int wrow = (wave & 1) * 32;
    const int wpix = (wave >> 1) * 64;

    f32x4 acc[2][4];
    #pragma unroll
    for (int m = 0; m < 2; ++m)
        #pragma unroll
        for (int n = 0; n < 4; ++n) { acc[m][n][0]=0.f; acc[m][n][1]=0.f; acc[m][n][2]=0.f; acc[m][n][3]=0.f; }

    const size_t xrow = ((size_t)b * HW + pixbase) * 128;

    #pragma unroll
    for (int kc = 0; kc < 2; ++kc) {
        if (kc) __syncthreads();
        // x stage: 16 segs/array, wave owns 4
        #pragma unroll
        for (int i = 0; i < 4; ++i) {
            int sgl = wave * 4 + i;
            int pix = sgl * 8 + (lane >> 3);
            int j = lane & 7;
            const _Float16* gh = xh_t + xrow + (size_t)pix * 128 + kc * 64 + j * 8;
            const _Float16* gl = xl_t + xrow + (size_t)pix * 128 + kc * 64 + j * 8;
            gl_lds16(gh, (void*)(xsh + sgl * 512));
            gl_lds16(gl, (void*)(xsl + sgl * 512));
        }
        // w stage: 8 segs/array, wave owns 2
        #pragma unroll
        for (int i = 0; i < 2; ++i) {
            int sgl = wave * 2 + i;
            int o = sgl * 8 + (lane >> 3);
            int j = lane & 7;
            const _Float16* gh = wh_t + (size_t)(outbase + o) * 128 + kc * 64 + j * 8;
            const _Float16* gl = wl_t + (size_t)(outbase + o) * 128 + kc * 64 + j * 8;
            gl_lds16(gh, (void*)(wsh + sgl * 512));
            gl_lds16(gl, (void*)(wsl + sgl * 512));
        }
        __syncthreads();

        #pragma unroll
        for (int ks = 0; ks < 2; ++ks) {
            const int kb = ks * 32 + (lane >> 4) * 8;
            half8 ah[2], al[2];
            #pragma unroll
            for (int m = 0; m < 2; ++m) {
                int o = wrow + m * 16 + (lane & 15);
                int idx = (o * 64 + kb) ^ ((o & 7) << 3);
                ah[m] = *(const half8*)&wsh[idx];
                al[m] = *(const half8*)&wsl[idx];
            }
            #pragma unroll
            for (int n = 0; n < 4; ++n) {
                int p = wpix + n * 16 + (lane & 15);
                int idx = (p * 64 + kb) ^ ((p & 7) << 3);
                half8 bh = *(const half8*)&xsh[idx];
                half8 bl = *(const half8*)&xsl[idx];
                mfma16(acc[0][n], ah[0], bh);
                mfma16(acc[1][n], ah[1], bh);
                mfma16(acc[0][n], al[0], bh);
                mfma16(acc[1][n], al[1], bh);
                mfma16(acc[0][n], ah[0], bl);
                mfma16(acc[1][n], ah[1], bl);
            }
        }
    }

    // MFMA->VALU read hazard guard
    asm volatile("s_nop 7\n\ts_nop 7"
        : "+v"(acc[0][0]), "+v"(acc[0][1]), "+v"(acc[0][2]), "+v"(acc[0][3]),
          "+v"(acc[1][0]), "+v"(acc[1][1]), "+v"(acc[1][2]), "+v"(acc[1][3]));

    float* base = (mt < 2) ? qbuf : kbuf;
    #pragma unroll
    for (int m = 0; m < 2; ++m) {
        #pragma unroll
        for (int n = 0; n < 4; ++n) {
            int pc = pixbase + wpix + n * 16 + (lane & 15);
            #pragma unroll
            for (int r = 0; r < 4; ++r) {
                int rowp = (mt & 1) * 64 + wrow + m * 16 + (lane >> 4) * 4 + r;
                base[((size_t)b * COUT + rowp) * HW + pc] = acc[m][n][r];
            }
        }
    }
}

// ---------------- Kernel 2: windowed softmax attention (v3, unchanged) ----------------
__global__ __launch_bounds__(192) void attn_v3(
    const float* __restrict__ qbuf,
    const float* __restrict__ kbuf,
    const float* __restrict__ v,
    const float* __restrict__ rel_h,
    const float* __restrict__ rel_w,
    float* __restrict__ out)
{
    __shared__ __align__(16) float ks[22 * 104];
    __shared__ __align__(16) float vs[22 * 104];

    const int tid = threadIdx.x;
    const int th = blockIdx.x * 16;
    const int bc = blockIdx.y;
    const int c = bc & 127;

    const float* kp = kbuf + (size_t)bc * HW;
    const float* vp = v    + (size_t)bc * HW;

    for (int idx = tid; idx < 22 * 102; idx += 192) {
        int r = idx / 102, cl = idx - r * 102;
        int gr = th - 3 + r, gc = cl - 3;
        bool ok = ((unsigned)gr < 96u) && ((unsigned)gc < 96u);
        float kv = ok ? kp[gr * 96 + gc] : 0.f;
        float vv = ok ? vp[gr * 96 + gc] : 0.f;
        ks[r * 104 + cl] = kv;
        vs[r * 104 + cl] = vv;
    }

    const bool is_h = (c < 64);
    const float* rbase = is_h ? (rel_h + c * 7) : (rel_w + (c - 64) * 7);
    float r7[7];
    #pragma unroll
    for (int i = 0; i < 7; ++i) r7[i] = rbase[i];

    const int ty = tid / 12;
    const int tx = tid - ty * 12;

    const float* qrow = qbuf + (size_t)bc * HW + (th + ty) * 96 + tx * 8;
    float4 qa = *(const float4*)qrow;
    float4 qb = *(const float4*)(qrow + 4);
    const float L2E = 1.4426950408889634f;
    float q2[8] = {qa.x * L2E, qa.y * L2E, qa.z * L2E, qa.w * L2E,
                   qb.x * L2E, qb.y * L2E, qb.z * L2E, qb.w * L2E};

    float s[8], a[8];
    #pragma unroll
    for (int j = 0; j < 8; ++j) { s[j] = 0.f; a[j] = 0.f; }

    __syncthreads();

    const float* krow = &ks[ty * 104 + tx * 8];
    const float* vrow = &vs[ty * 104 + tx * 8];

    #pragma unroll
    for (int dh = 0; dh < 7; ++dh) {
        float kr[16], vr[16];
        #pragma unroll
        for (int t = 0; t < 4; ++t) {
            *(float4*)&kr[t * 4] = *(const float4*)&krow[t * 4];
            *(float4*)&vr[t * 4] = *(const float4*)&vrow[t * 4];
        }
        krow += 104;
        vrow += 104;

        if (is_h) {
            float rh = r7[dh];
            #pragma unroll
            for (int j = 0; j < 8; ++j) {
                float qr = q2[j] * rh;
                #pragma unroll
                for (int dw = 0; dw < 7; ++dw) {
                    float e = fast_exp2(fmaf(q2[j], kr[j + dw], qr));
                    s[j] += e;
                    a[j] = fmaf(e, vr[j + dw], a[j]);
                }
            }
        } else {
            #pragma unroll
            for (int j = 0; j < 8; ++j) {
                #pragma unroll
                for (int dw = 0; dw < 7; ++dw) {
                    float e = fast_exp2(q2[j] * (kr[j + dw] + r7[dw]));
                    s[j] += e;
                    a[j] = fmaf(e, vr[j + dw], a[j]);
                }
            }
        }
    }

    float* orow = out + (size_t)bc * HW + (th + ty) * 96 + tx * 8;
    float4 o0, o1;
    o0.x = a[0] * __builtin_amdgcn_rcpf(s[0]);
    o0.y = a[1] * __builtin_amdgcn_rcpf(s[1]);
    o0.z = a[2] * __builtin_amdgcn_rcpf(s[2]);
    o0.w = a[3] * __builtin_amdgcn_rcpf(s[3]);
    o1.x = a[4] * __builtin_amdgcn_rcpf(s[4]);
    o1.y = a[5] * __builtin_amdgcn_rcpf(s[5]);
    o1.z = a[6] * __builtin_amdgcn_rcpf(s[6]);
    o1.w = a[7] * __builtin_amdgcn_rcpf(s[7]);
    *(float4*)orow = o0;
    *(float4*)(orow + 4) = o1;
}

extern "C" void kernel_launch(void* const* d_in, const int* in_sizes, int n_in,
                              void* d_out, int out_size, void* d_ws, size_t ws_size,
                              hipStream_t stream) {
    const float* x  = (const float*)d_in[0];
    const float* v  = (const float*)d_in[1];
    const float* wq = (const float*)d_in[2];
    const float* wk = (const float*)d_in[3];
    const float* rh = (const float*)d_in[4];
    const float* rw = (const float*)d_in[5];
    float* out = (float*)d_out;

    float* qbuf = (float*)d_ws;                         // 2*128*9216 f32
    float* kbuf = qbuf + (size_t)2 * COUT * HW;
    _Float16* xh = (_Float16*)(kbuf + (size_t)2 * COUT * HW);
    _Float16* xl = xh + (size_t)2 * HW * 128;
    _Float16* wh = xl + (size_t)2 * HW * 128;
    _Float16* wl = wh + 256 * 128;

    prep<<<dim3(152, 2), 256, 0, stream>>>(x, wq, wk, xh, xl, wh, wl);
    conv_mfma<<<dim3(72, 2, 4), 256, 0, stream>>>(xh, xl, wh, wl, qbuf, kbuf);
    attn_v3<<<dim3(6, 256), 192, 0, stream>>>(qbuf, kbuf, v, rh, rw, out);
}